// Round 6
// baseline (347.609 us; speedup 1.0000x reference)
//
#include <hip/hip_runtime.h>

// Problem constants
#define BB    4
#define LL    4096
#define DM    1024
#define HH    16
#define SEGC  64
#define HDC   64
#define NSEGC 64
#define NEGV  -1.0e10f

typedef __bf16 bf16x8 __attribute__((ext_vector_type(8)));
typedef float  f32x4  __attribute__((ext_vector_type(4)));

__device__ __forceinline__ float bf2f(unsigned short s) {
  union { unsigned int u; float f; } x; x.u = ((unsigned int)s) << 16; return x.f;
}
__device__ __forceinline__ unsigned short f2bf(float f) {
  union { float f; unsigned int u; } x; x.f = f;
  unsigned int u = x.u;
  return (unsigned short)((u + 0x7fffu + ((u >> 16) & 1u)) >> 16);
}

// async global->LDS, 16 bytes per lane; LDS dest is wave-uniform base,
// lane i lands at l + i*16 bytes.
__device__ __forceinline__ void gl2lds16(const unsigned short* g, unsigned short* l) {
  __builtin_amdgcn_global_load_lds(
      (const __attribute__((address_space(1))) unsigned int*)g,
      (__attribute__((address_space(3))) unsigned int*)l,
      16, 0, 0);
}

// copy 16 bf16 from global (16B-aligned) to LDS (4B-aligned) via VGPR
__device__ __forceinline__ void g2lds16(unsigned short* dst, const unsigned short* src) {
  int4 a = *(const int4*)(src);
  int4 b = *(const int4*)(src + 8);
  unsigned int* d = (unsigned int*)dst;
  const unsigned int* pa = (const unsigned int*)&a;
  const unsigned int* pb = (const unsigned int*)&b;
  d[0]=pa[0]; d[1]=pa[1]; d[2]=pa[2]; d[3]=pa[3];
  d[4]=pb[0]; d[5]=pb[1]; d[6]=pb[2]; d[7]=pb[3];
}

// ---------------------------------------------------------------------------
// prep: merged weight-transpose (blocks 0..1023) + x f32->bf16 (blocks 1024+).
// Saves one kernel launch + serialization gap vs separate cvt_x/transpose_w.
// ---------------------------------------------------------------------------
__global__ __launch_bounds__(256) void prep(
    const float* __restrict__ x,
    const float* __restrict__ wq, const float* __restrict__ wk,
    const float* __restrict__ wv, const float* __restrict__ wo,
    unsigned short* __restrict__ xb,
    unsigned short* __restrict__ WqkvT, unsigned short* __restrict__ woT) {
  __shared__ unsigned short TS[64 * 65];
  const int bid = blockIdx.x;
  const int t   = threadIdx.x;

  if (bid >= 1024) {
    // ---- cvt region: f32 -> bf16, 8 elems/thread
    const size_t i = ((size_t)(bid - 1024) * 256 + t) * 8;
    float4 a = *(const float4*)(x + i);
    float4 b = *(const float4*)(x + i + 4);
    unsigned short o[8];
    o[0]=f2bf(a.x); o[1]=f2bf(a.y); o[2]=f2bf(a.z); o[3]=f2bf(a.w);
    o[4]=f2bf(b.x); o[5]=f2bf(b.y); o[6]=f2bf(b.z); o[7]=f2bf(b.w);
    *(int4*)(xb + i) = *(const int4*)o;
    return;
  }

  // ---- transpose region: 64x64 tile of one weight matrix
  const int z  = bid >> 8;
  const int bx = bid & 15;
  const int by = (bid >> 4) & 15;

  const float* src; unsigned short* dst; float scale = 1.0f;
  if (z == 0)      { src = wq; dst = WqkvT;               scale = 0.125f; }
  else if (z == 1) { src = wk; dst = WqkvT + 1024 * 1024; }
  else if (z == 2) { src = wv; dst = WqkvT + 2048 * 1024; }
  else             { src = wo; dst = woT; }

  const int rr = t >> 4;
  const int c4 = (t & 15) * 4;
  #pragma unroll
  for (int it = 0; it < 4; it++) {
    const int r = it * 16 + rr;
    float4 f = *(const float4*)(src + (size_t)(by * 64 + r) * 1024 + bx * 64 + c4);
    TS[(c4 + 0) * 65 + r] = f2bf(f.x * scale);
    TS[(c4 + 1) * 65 + r] = f2bf(f.y * scale);
    TS[(c4 + 2) * 65 + r] = f2bf(f.z * scale);
    TS[(c4 + 3) * 65 + r] = f2bf(f.w * scale);
  }
  __syncthreads();

  const int wr = t >> 3;
  const int w8 = (t & 7) * 8;
  #pragma unroll
  for (int it = 0; it < 2; it++) {
    const int n = it * 32 + wr;
    unsigned short o[8];
    #pragma unroll
    for (int j = 0; j < 8; j++) o[j] = TS[n * 65 + w8 + j];
    *(int4*)(dst + (size_t)(bx * 64 + n) * 1024 + by * 64 + w8) = *(const int4*)o;
  }
}

// ---------------------------------------------------------------------------
// gemm256 (v1 schedule, best measured ~111.5 us): C = A @ Bt^T (bf16, f32 acc)
// 256x256 tile, BK=64, 8 waves (2M x 4N), 128 KiB LDS double-buffer,
// 8-phase counted-vmcnt schedule, st_16x32 swizzle via pre-swizzled source,
// setprio around MFMA clusters, bijective XCD swizzle.
// ---------------------------------------------------------------------------
template <bool C_F32>
__global__ __launch_bounds__(512, 2) void gemm256(
    const unsigned short* __restrict__ A,
    const unsigned short* __restrict__ Bt,
    void* __restrict__ Cv,
    int ldc)
{
  // [buf][mat A=0/B=1][quarter][4096 ushorts = 8KB]
  __shared__ __align__(16) unsigned short L[2][2][4][4096];

  const int t    = threadIdx.x;
  const int wave = t >> 6;
  const int lane = t & 63;
  const int l15  = lane & 15;
  const int q4   = lane >> 4;
  const int wm   = wave >> 2;        // 0..1 : 128-row band
  const int wn   = wave & 3;         // 0..3 : 64-col band

  const int nwg = gridDim.x;
  const int wg  = blockIdx.x;
  const int swz = (wg & 7) * (nwg >> 3) + (wg >> 3);
  const int m0  = (swz & 63) << 8;   // 64 m-tiles (M = 16384)
  const int n0  = (swz >> 6) << 8;

  const int srow = ((wave >> 1) << 4) + (lane >> 2);
  const int scol = ((wave & 1) << 5) + (((lane & 3) << 3) ^ (((lane >> 5) & 1) << 4));
  const size_t laneoff = (size_t)srow * 1024 + scol;
  const unsigned short* Ab = A  + (size_t)m0 * 1024 + laneoff;
  const unsigned short* Bb = Bt + (size_t)n0 * 1024 + laneoff;

  const int rdoff = l15 * 32 + ((q4 * 8) ^ (((l15 >> 3) & 1) << 4));

#define SA_(d, q, kt) gl2lds16(Ab + ((size_t)(q) * 64) * 1024 + (size_t)(kt) * 64, \
                               &L[d][0][q][0] + wave * 512)
#define SB_(d, q, kt) gl2lds16(Bb + ((size_t)(q) * 64) * 1024 + (size_t)(kt) * 64, \
                               &L[d][1][q][0] + wave * 512)
#define LDA8(d, i, kk) (*(const bf16x8*)(&L[d][0][wm * 2 + ((i) >> 2)][0] + \
                        ((((i) & 3) * 2 + (kk)) * 512) + rdoff))
#define LDB8(d, j, kk) (*(const bf16x8*)(&L[d][1][wn][0] + \
                        ((((j) * 2 + (kk))) * 512) + rdoff))
#define BAR()   asm volatile("s_barrier" ::: "memory")
#define LGKM0() asm volatile("s_waitcnt lgkmcnt(0)" ::: "memory")
#define VMW(n)  asm volatile("s_waitcnt vmcnt(" #n ")" ::: "memory")
#define MFMA_(av, bv, cv) __builtin_amdgcn_mfma_f32_16x16x32_bf16(av, bv, cv, 0, 0, 0)

  f32x4 acc[8][4];
  #pragma unroll
  for (int i = 0; i < 8; ++i)
    #pragma unroll
    for (int j = 0; j < 4; ++j) acc[i][j] = (f32x4){0.f, 0.f, 0.f, 0.f};

  // Prologue:
  SB_(0,0,0); SB_(0,1,0); SB_(0,2,0); SB_(0,3,0); SA_(0,0,0); SA_(0,2,0);
  SA_(0,1,0); SA_(0,3,0);
  SB_(1,0,1); SB_(1,1,1); SB_(1,2,1); SB_(1,3,1); SA_(1,0,1); SA_(1,2,1);
  VMW(8); BAR();   // T0:{Bq*,Aq0,Aq2} landed; 8 in flight

  #pragma unroll 1
  for (int it = 0; it < 8; ++it) {
    const int t1 = 2 * it + 1;
    const int s2 = (2 * it + 2) & 15;
    const int s3 = (2 * it + 3) & 15;
    bf16x8 a[4][2], b[4][2];

    // ---- P0
    #pragma unroll
    for (int ii = 0; ii < 4; ++ii) { a[ii][0] = LDA8(0, ii, 0); a[ii][1] = LDA8(0, ii, 1); }
    #pragma unroll
    for (int jj = 0; jj < 4; ++jj) { b[jj][0] = LDB8(0, jj, 0); b[jj][1] = LDB8(0, jj, 1); }
    SA_(1, 1, t1); SA_(1, 3, t1);
    BAR(); LGKM0();
    __builtin_amdgcn_s_setprio(1);
    #pragma unroll
    for (int ii = 0; ii < 4; ++ii)
      #pragma unroll
      for (int jj = 0; jj < 2; ++jj) {
        acc[ii][jj] = MFMA_(a[ii][0], b[jj][0], acc[ii][jj]);
        acc[ii][jj] = MFMA_(a[ii][1], b[jj][1], acc[ii][jj]);
      }
    __builtin_amdgcn_s_setprio(0);
    BAR();

    // ---- P1
    SB_(0, 0, s2); SB_(0, 1, s2);
    BAR();
    __builtin_amdgcn_s_setprio(1);
    #pragma unroll
    for (int ii = 0; ii < 4; ++ii)
      #pragma unroll
      for (int jj = 2; jj < 4; ++jj) {
        acc[ii][jj] = MFMA_(a[ii][0], b[jj][0], acc[ii][jj]);
        acc[ii][jj] = MFMA_(a[ii][1], b[jj][1], acc[ii][jj]);
      }
    __builtin_amdgcn_s_setprio(0);
    VMW(10); BAR();

    // ---- P2
    #pragma unroll
    for (int ii = 0; ii < 4; ++ii) { a[ii][0] = LDA8(0, 4 + ii, 0); a[ii][1] = LDA8(0, 4 + ii, 1); }
    SB_(0, 2, s2); SB_(0, 3, s2);
    BAR(); LGKM0();
    __builtin_amdgcn_s_setprio(1);
    #pragma unroll
    for (int ii = 0; ii < 4; ++ii)
      #pragma unroll
      for (int jj = 2; jj < 4; ++jj) {
        acc[4 + ii][jj] = MFMA_(a[ii][0], b[jj][0], acc[4 + ii][jj]);
        acc[4 + ii][jj] = MFMA_(a[ii][1], b[jj][1], acc[4 + ii][jj]);
      }
    __builtin_amdgcn_s_setprio(0);
    BAR();

    // ---- P3
    SA_(0, 0, s2); SA_(0, 2, s2);
    BAR();
    __builtin_amdgcn_s_setprio(1);
    #pragma unroll
    for (int ii = 0; ii < 4; ++ii)
      #pragma unroll
      for (int jj = 0; jj < 2; ++jj) {
        acc[4 + ii][jj] = MFMA_(a[ii][0], b[jj][0], acc[4 + ii][jj]);
        acc[4 + ii][jj] = MFMA_(a[ii][1], b[jj][1], acc[4 + ii][jj]);
      }
    __builtin_amdgcn_s_setprio(0);
    VMW(8); BAR();

    // ---- P4
    #pragma unroll
    for (int ii = 0; ii < 4; ++ii) { a[ii][0] = LDA8(1, ii, 0); a[ii][1] = LDA8(1, ii, 1); }
    #pragma unroll
    for (int jj = 0; jj < 4; ++jj) { b[jj][0] = LDB8(1, jj, 0); b[jj][1] = LDB8(1, jj, 1); }
    SA_(0, 1, s2); SA_(0, 3, s2);
    BAR(); LGKM0();
    __builtin_amdgcn_s_setprio(1);
    #pragma unroll
    for (int ii = 0; ii < 4; ++ii)
      #pragma unroll
      for (int jj = 0; jj < 2; ++jj) {
        acc[ii][jj] = MFMA_(a[ii][0], b[jj][0], acc[ii][jj]);
        acc[ii][jj] = MFMA_(a[ii][1], b[jj][1], acc[ii][jj]);
      }
    __builtin_amdgcn_s_setprio(0);
    BAR();

    // ---- P5
    SB_(1, 0, s3); SB_(1, 1, s3);
    BAR();
    __builtin_amdgcn_s_setprio(1);
    #pragma unroll
    for (int ii = 0; ii < 4; ++ii)
      #pragma unroll
      for (int jj = 2; jj < 4; ++jj) {
        acc[ii][jj] = MFMA_(a[ii][0], b[jj][0], acc[ii][jj]);
        acc[ii][jj] = MFMA_(a[ii][1], b[jj][1], acc[ii][jj]);
      }
    __builtin_amdgcn_s_setprio(0);
    VMW(10); BAR();

    // ---- P6
    #pragma unroll
    for (int ii = 0; ii < 4; ++ii) { a[ii][0] = LDA8(1, 4 + ii, 0); a[ii][1] = LDA8(1, 4 + ii, 1); }
    SB_(1, 2, s3); SB_(1, 3, s3);
    BAR(); LGKM0();
    __builtin_amdgcn_s_setprio(1);
    #pragma unroll
    for (int ii = 0; ii < 4; ++ii)
      #pragma unroll
      for (int jj = 2; jj < 4; ++jj) {
        acc[4 + ii][jj] = MFMA_(a[ii][0], b[jj][0], acc[4 + ii][jj]);
        acc[4 + ii][jj] = MFMA_(a[ii][1], b[jj][1], acc[4 + ii][jj]);
      }
    __builtin_amdgcn_s_setprio(0);
    BAR();

    // ---- P7
    SA_(1, 0, s3); SA_(1, 2, s3);
    BAR();
    __builtin_amdgcn_s_setprio(1);
    #pragma unroll
    for (int ii = 0; ii < 4; ++ii)
      #pragma unroll
      for (int jj = 0; jj < 2; ++jj) {
        acc[4 + ii][jj] = MFMA_(a[ii][0], b[jj][0], acc[4 + ii][jj]);
        acc[4 + ii][jj] = MFMA_(a[ii][1], b[jj][1], acc[4 + ii][jj]);
      }
    __builtin_amdgcn_s_setprio(0);
    VMW(8); BAR();
  }

  // Epilogue: C write (each wave owns 128x64 at (wm*128, wn*64))
  #pragma unroll
  for (int i = 0; i < 8; ++i) {
    #pragma unroll
    for (int j = 0; j < 4; ++j) {
      const int col = n0 + wn * 64 + j * 16 + l15;
      #pragma unroll
      for (int r = 0; r < 4; ++r) {
        const int row = m0 + wm * 128 + i * 16 + q4 * 4 + r;
        if (C_F32) ((float*)Cv)[(size_t)row * ldc + col] = acc[i][j][r];
        else ((unsigned short*)Cv)[(size_t)row * ldc + col] = f2bf(acc[i][j][r]);
      }
    }
  }
  VMW(0);  // drain straggler LDS-DMA before endpgm (next block reuses this LDS)

#undef SA_
#undef SB_
#undef LDA8
#undef LDB8
#undef BAR
#undef LGKM0
#undef VMW
#undef MFMA_
}

// ---------------------------------------------------------------------------
// Span kernel v3: one 256-thread block per chunk c (grid 256), all 16 heads.
// Thread t owns 4 columns d = 4t..4t+3 (head h = t>>4, lane-in-head = t&15).
// Every global access is a fully-coalesced 2KB row read (256 x 8B).
// mq / col-max live in registers; logits via 16-lane shfl reduce; softmax
// wave-local; V-pass reads weights via LDS broadcast. No Q/K/V staging.
// ---------------------------------------------------------------------------
__global__ __launch_bounds__(256) void span_kernel(
    const unsigned short* __restrict__ qkv,
    unsigned short* __restrict__ spanK,   // [256][16][64]
    unsigned short* __restrict__ spanV)   // [256][16][64]
{
  __shared__ float lgs[16 * 64];   // logits [h][k]
  __shared__ float wss[16 * 64];   // weights [h][k]

  const int c  = blockIdx.x;       // 0..255
  const int b  = c >> 6, n = c & 63;
  const int t  = threadIdx.x;      // 0..255
  const int h  = t >> 4;           // head 0..15
  const int lh = t & 15;           // lane-in-head
  const int d0 = t * 4;            // global col 0..1020

  const unsigned short* base = qkv + ((size_t)(b * LL + n * SEGC)) * 3072;

  // ---- Pass 1: Q column max -> registers
  float mq0 = -3.0e38f, mq1 = -3.0e38f, mq2 = -3.0e38f, mq3 = -3.0e38f;
  #pragma unroll 8
  for (int r = 0; r < 64; ++r) {
    unsigned long long v = *(const unsigned long long*)(base + (size_t)r * 3072 + d0);
    mq0 = fmaxf(mq0, bf2f((unsigned short)(v      )));
    mq1 = fmaxf(mq1, bf2f((unsigned short)(v >> 16)));
    mq2 = fmaxf(mq2, bf2f((unsigned short)(v >> 32)));
    mq3 = fmaxf(mq3, bf2f((unsigned short)(v >> 48)));
  }

  // ---- Pass 2: K column max (spanK) + logits (mq . K row, reduced per head)
  float km0 = -3.0e38f, km1 = -3.0e38f, km2 = -3.0e38f, km3 = -3.0e38f;
  #pragma unroll 4
  for (int k = 0; k < 64; ++k) {
    unsigned long long v = *(const unsigned long long*)(base + (size_t)k * 3072 + 1024 + d0);
    const float f0 = bf2f((unsigned short)(v      ));
    const float f1 = bf2f((unsigned short)(v >> 16));
    const float f2 = bf2f((unsigned short)(v >> 32));
    const float f3 = bf2f((unsigned short)(v >> 48));
    km0 = fmaxf(km0, f0); km1 = fmaxf(km1, f1);
    km2 = fmaxf(km2, f2); km3 = fmaxf(km3, f3);
    float p = mq0 * f0 + mq1 * f1 + mq2 * f2 + mq3 * f3;
    p += __shfl_xor(p, 1, 64); p += __shfl_xor(p, 2, 64);
    p += __shfl_xor(p, 4, 64); p += __shfl_xor(p, 8, 64);
    if (lh == 0) lgs[h * 64 + k] = p;
  }
  {
    unsigned short o[4] = { f2bf(km0), f2bf(km1), f2bf(km2), f2bf(km3) };
    *(unsigned long long*)(spanK + ((size_t)c * 16 + h) * 64 + lh * 4) =
        *(const unsigned long long*)o;
  }
  __syncthreads();

  // ---- softmax per head over 64 k (thread handles k = lh*4 .. lh*4+3)
  {
    const float l0 = lgs[h * 64 + lh * 4 + 0];
    const float l1 = lgs[h * 64 + lh * 4 + 1];
    const float l2 = lgs[h * 64 + lh * 4 + 2];
    const float l3 = lgs[h * 64 + lh * 4 + 3];
    float mx = fmaxf(fmaxf(l0, l1), fmaxf(l2, l3));
    mx = fmaxf(mx, __shfl_xor(mx, 1, 64)); mx = fmaxf(mx, __shfl_xor(mx, 2, 64));
    mx = fmaxf(mx, __shfl_xor(mx, 4, 64)); mx = fmaxf(mx, __shfl_xor(mx, 8, 64));
    const float e0 = __expf(l0 - mx), e1 = __expf(l1 - mx);
    const float e2 = __expf(l2 - mx), e3 = __expf(l3 - mx);
    float s = e0 + e1 + e2 + e3;
    s += __shfl_xor(s, 1, 64); s += __shfl_xor(s, 2, 64);
    s += __shfl_xor(s, 4, 64); s += __shfl_xor(s, 8, 64);
    const float inv = 1.0f / s;
    wss[h * 64 + lh * 4 + 0] = e0 * inv;
    wss[h * 64 + lh * 4 + 1] = e1 * inv;
    wss[h * 64 + lh * 4 + 2] = e2 * inv;
    wss[h * 64 + lh * 4 + 3] = e3 * inv;
  }
  __syncthreads();

  // ---- Pass 3: V weighted sum
  float sv0 = 0.f, sv1 = 0.f, sv2 = 0.f, sv3 = 0.f;
  #pragma unroll 8
  for (int k = 0; k < 64; ++k) {
    unsigned long long v = *(const unsigned long long*)(base + (size_t)k * 3072 + 2048 + d0);
    const float w = wss[h * 64 + k];   // LDS broadcast within 16-lane group
    sv0 += w * bf2f((unsigned short)(v      ));
    sv1 += w * bf2f((unsigned short)(v >> 16));
    sv2 += w * bf2f((unsigned short)(v >> 32));
    sv3 += w * bf2f((unsigned short)(v >> 48));
  }
  {
    unsigned short o[4] = { f2bf(sv0), f2bf(sv1), f2bf(sv2), f2bf(sv3) };
    *(unsigned long long*)(spanV + ((size_t)c * 16 + h) * 64 + lh * 4) =
        *(const unsigned long long*)o;
  }
}

// ---------------------------------------------------------------------------
// Joint attention kernel (MFMA): per (chunk c, head h), 4 waves.
// v3: K-joint (local K + spanK) staged into LDS KJ[128][72] via coalesced
// g2lds16 (4 threads/row = 128B contiguous). VT staging keeps the v2 XOR
// swizzle (element-verified in round 3).
// ---------------------------------------------------------------------------
__global__ __launch_bounds__(256) void attn_kernel(
    const unsigned short* __restrict__ qkv,
    const unsigned short* __restrict__ spanK,
    const unsigned short* __restrict__ spanV,
    unsigned short* __restrict__ att)
{
  __shared__ __align__(16) unsigned short KJ[128 * 72];  // [r][72]: r<64 local K, r>=64 spanK
  __shared__ __align__(16) unsigned short VT[64 * 136];  // [f][k'-swizzled]
  __shared__ __align__(16) unsigned short WL[64 * 136];  // [att row][k'] weights

  const int c = blockIdx.x;
  const int h = blockIdx.y;
  const int b = c >> 6, n = c & 63;
  const int t = threadIdx.x;
  const int wave = t >> 6;
  const int lane = t & 63;
  const int l15  = lane & 15;
  const int q4   = lane >> 4;

  // ---- stage K-joint into KJ (coalesced: 4 threads x 32B = 128B per row)
  {
    const int r  = t >> 2;            // 0..63
    const int qq = (t & 3) * 16;      // 0,16,32,48 (u16)
    g2lds16(KJ + r * 72 + qq,
            qkv + ((size_t)(b * LL + n * SEGC + r)) * 3072 + 1024 + h * 64 + qq);
    g2lds16(KJ + (64 + r) * 72 + qq,
            spanK + ((size_t)(b * 64 + r) * 16 + h) * 64 + qq);
  }

  // ---- stage V' transposed into VT (v2 swizzle)
  #pragma unroll
  for (int it = 0; it < 4; it++) {
    const int idx = t + 256 * it;
    const int kp  = idx >> 3;           // joint key 0..127
    const int fc  = (idx & 7) * 8;
    const unsigned short* src;
    if (kp < 64)
      src = qkv + ((size_t)(b * LL + n * SEGC + kp)) * 3072 + 2048 + h * 64 + fc;
    else
      src = spanV + ((size_t)(b * 64 + (kp - 64)) * 16 + h) * 64 + fc;
    int4 val = *(const int4*)src;
    const unsigned short* e = (const unsigned short*)&val;
    const int kb = kp >> 3;             // k'-block 0..15
    #pragma unroll
    for (int i = 0; i < 8; i++) {
      const int f  = fc + i;
      const int nb = (kb & 8) | ((kb ^ (f >> 3)) & 7);   // swizzled block
      VT[f * 136 + nb * 8 + (kp & 7)] = e[i];
    }
  }

  // Q fragments: direct global (read once, no reuse)
  bf16x8 af[2];
  {
    const size_t qbase = ((size_t)(b * LL + n * SEGC + wave * 16 + l15)) * 3072
                         + h * 64 + q4 * 8;
    af[0] = *(const bf16x8*)(qkv + qbase);
    af[1] = *(const bf16x8*)(qkv + qbase + 32);
  }

  __syncthreads();   // KJ + VT complete

  f32x4 accl[8];
  #pragma unroll
  for (int tt = 0; tt < 8; tt++) accl[tt] = (f32x4){0.f, 0.f, 0.f, 0.f};

  #pragma unroll
  for (int s = 0; s < 2; s++) {
    bf16x8 bfr[8];
    #pragma unroll
    for (int tt = 0; tt < 8; tt++)
      bfr[tt] = *(const bf16x8*)(KJ + (tt * 16 + l15) * 72 + s * 32 + q4 * 8);
    #pragma unroll
    for (int tt = 0; tt < 8; tt++)
      accl[tt] = __builtin_amdgcn_mfma_f32_16x16x32_bf16(af[s], bfr[tt], accl[tt], 0, 0, 0);
  }

  #pragma unroll
  for (int tt = 0; tt < 8; tt++) {
    const int col = (tt & 3) * 16 + l15;
    #pragma unroll
    for (int rr = 0; rr < 4; rr++) {
      const int r_att = wave * 16 + q4 * 4 + rr;
      const bool valid = (tt < 4) ? (col <= r_att) : (col < n);
      if (!valid) accl[tt][rr] = NEGV;
    }
  }

  #pragma unroll
  for (int rr = 0; rr < 4; rr++) {
    float mx = accl[0][rr];
    #pragma unroll
    for (int tt = 1; tt < 8; tt++) mx = fmaxf(mx, accl[tt][rr]);
    #pragma unroll
    for (int msk = 1; msk < 16; msk <<= 1) mx = fmaxf(mx, __shfl_xor(mx, msk, 64));
    float sm = 0.f;
    float ex[8];
    #pragma unroll
    for (int tt = 0; tt < 8; tt++) { ex[tt] = __expf(accl[tt][rr] - mx); sm += ex[tt]; }
    #pragma unroll
    for (int msk = 1; msk < 16; msk <<= 1) sm += __shfl_xor(sm, msk, 64);
    const float inv = 1.0f / sm;
    const int r_att = wave * 16 + q4 * 4 + rr;
    #pragma unroll
    for (int tt = 0; tt < 8; tt++) {
      const int colj = (tt < 4) ? (tt * 16 + l15) : (64 + (tt - 4) * 16 + l15);
      WL[r_att * 136 + colj] = f2bf(ex[tt] * inv);
    }
  }

  __syncthreads();

  f32x4 accm[4];
  #pragma unroll
  for (int j = 0; j < 4; j++) accm[j] = (f32x4){0.f, 0.f, 0.f, 0.f};
  #pragma unroll
  for (int s = 0; s < 4; s++) {
    const bf16x8 aw = *(const bf16x8*)(WL + (wave * 16 + l15) * 136 + s * 32 + q4 * 8);
    #pragma unroll
    for (int j = 0; j < 4; j++) {
      const int f  = j * 16 + l15;
      const int kb = s * 4 + q4;                          // k'-block 0..15
      const int nb = (kb & 8) | ((kb ^ (f >> 3)) & 7);    // same swizzle as write
      const bf16x8 bv = *(const bf16x8*)(VT + f * 136 + nb * 8);
      accm[j] = __builtin_amdgcn_mfma_f32_16x16x32_bf16(aw, bv, accm[j], 0, 0, 0);
    }
  }

  #pragma unroll
  for (int j = 0; j < 4; j++) {
    #pragma unroll
    for (int rr = 0; rr < 4; rr++) {
      const int row = wave * 16 + q4 * 4 + rr;
      const int col = j * 16 + l15;
      att[((size_t)(b * LL + n * SEGC + row)) * 1024 + h * 64 + col] = f2bf(accm[j][rr]);
    }
  }
}

// ---------------------------------------------------------------------------
extern "C" void kernel_launch(void* const* d_in, const int* in_sizes, int n_in,
                              void* d_out, int out_size, void* d_ws, size_t ws_size,
                              hipStream_t stream) {
  const float* x  = (const float*)d_in[0];
  const float* wq = (const float*)d_in[1];
  const float* wk = (const float*)d_in[2];
  const float* wv = (const float*)d_in[3];
  const float* wo = (const float*)d_in[4];
  float* out = (float*)d_out;

  unsigned short* wsp   = (unsigned short*)d_ws;
  unsigned short* xb    = wsp;                       // 16,777,216 (aliased as attb later)
  unsigned short* qkv   = xb + 16777216;             // 50,331,648
  unsigned short* WqkvT = qkv + 50331648;            //  3,145,728
  unsigned short* woT   = WqkvT + 3145728;           //  1,048,576
  unsigned short* skb   = woT + 1048576;             //    262,144
  unsigned short* svb   = skb + 262144;              //    262,144
  unsigned short* attb  = xb;   // alias: xb dead after QKV GEMM

  // prep: blocks 0..1023 = weight transpose, 1024..9215 = x cvt
  prep<<<9216, 256, 0, stream>>>(x, wq, wk, wv, wo, xb, WqkvT, woT);
  // QKV: M=16384, N=3072 -> 64 x 12 = 768 tiles (768 % 8 == 0)
  gemm256<false><<<768, 512, 0, stream>>>(xb, WqkvT, (void*)qkv, 3072);
  span_kernel<<<256, 256, 0, stream>>>(qkv, skb, svb);
  attn_kernel<<<dim3(256, 16), 256, 0, stream>>>(qkv, skb, svb, attb);
  // out-proj: M=16384, N=1024 -> 64 x 4 = 256 tiles (256 % 8 == 0)
  gemm256<true><<<256, 512, 0, stream>>>(attb, woT, (void*)out, 1024);
}

// Round 7
// 321.036 us; speedup vs baseline: 1.0828x; 1.0828x over previous
//
#include <hip/hip_runtime.h>

// Problem constants
#define BB    4
#define LL    4096
#define DM    1024
#define HH    16
#define SEGC  64
#define HDC   64
#define NSEGC 64
#define NEGV  -1.0e10f

typedef __bf16 bf16x8 __attribute__((ext_vector_type(8)));
typedef float  f32x4  __attribute__((ext_vector_type(4)));

__device__ __forceinline__ float bf2f(unsigned short s) {
  union { unsigned int u; float f; } x; x.u = ((unsigned int)s) << 16; return x.f;
}
__device__ __forceinline__ unsigned short f2bf(float f) {
  union { float f; unsigned int u; } x; x.f = f;
  unsigned int u = x.u;
  return (unsigned short)((u + 0x7fffu + ((u >> 16) & 1u)) >> 16);
}

// async global->LDS, 16 bytes per lane; LDS dest is wave-uniform base,
// lane i lands at l + i*16 bytes.
__device__ __forceinline__ void gl2lds16(const unsigned short* g, unsigned short* l) {
  __builtin_amdgcn_global_load_lds(
      (const __attribute__((address_space(1))) unsigned int*)g,
      (__attribute__((address_space(3))) unsigned int*)l,
      16, 0, 0);
}

// copy 16 bf16 from global (16B-aligned) to LDS (4B-aligned) via VGPR
__device__ __forceinline__ void g2lds16(unsigned short* dst, const unsigned short* src) {
  int4 a = *(const int4*)(src);
  int4 b = *(const int4*)(src + 8);
  unsigned int* d = (unsigned int*)dst;
  const unsigned int* pa = (const unsigned int*)&a;
  const unsigned int* pb = (const unsigned int*)&b;
  d[0]=pa[0]; d[1]=pa[1]; d[2]=pa[2]; d[3]=pa[3];
  d[4]=pb[0]; d[5]=pb[1]; d[6]=pb[2]; d[7]=pb[3];
}

// ---------------------------------------------------------------------------
// cvt_x: f32 -> bf16, 8 elems/thread
// ---------------------------------------------------------------------------
__global__ __launch_bounds__(256) void cvt_x(const float* __restrict__ x,
                                             unsigned short* __restrict__ xb) {
  const size_t i = ((size_t)blockIdx.x * 256 + threadIdx.x) * 8;
  float4 a = *(const float4*)(x + i);
  float4 b = *(const float4*)(x + i + 4);
  unsigned short o[8];
  o[0]=f2bf(a.x); o[1]=f2bf(a.y); o[2]=f2bf(a.z); o[3]=f2bf(a.w);
  o[4]=f2bf(b.x); o[5]=f2bf(b.y); o[6]=f2bf(b.z); o[7]=f2bf(b.w);
  *(int4*)(xb + i) = *(const int4*)o;
}

// ---------------------------------------------------------------------------
// transpose_w: LDS tile-transpose f32[1024][1024] -> bf16 [N][K].
// ---------------------------------------------------------------------------
__global__ __launch_bounds__(256) void transpose_w(
    const float* __restrict__ wq, const float* __restrict__ wk,
    const float* __restrict__ wv, const float* __restrict__ wo,
    unsigned short* __restrict__ WqkvT, unsigned short* __restrict__ woT) {
  __shared__ unsigned short TS[64 * 65];

  const int z  = blockIdx.z;
  const int bx = blockIdx.x;
  const int by = blockIdx.y;
  const int t  = threadIdx.x;

  const float* src; unsigned short* dst; float scale = 1.0f;
  if (z == 0)      { src = wq; dst = WqkvT;               scale = 0.125f; }
  else if (z == 1) { src = wk; dst = WqkvT + 1024 * 1024; }
  else if (z == 2) { src = wv; dst = WqkvT + 2048 * 1024; }
  else             { src = wo; dst = woT; }

  const int rr = t >> 4;
  const int c4 = (t & 15) * 4;
  #pragma unroll
  for (int it = 0; it < 4; it++) {
    const int r = it * 16 + rr;
    float4 f = *(const float4*)(src + (size_t)(by * 64 + r) * 1024 + bx * 64 + c4);
    TS[(c4 + 0) * 65 + r] = f2bf(f.x * scale);
    TS[(c4 + 1) * 65 + r] = f2bf(f.y * scale);
    TS[(c4 + 2) * 65 + r] = f2bf(f.z * scale);
    TS[(c4 + 3) * 65 + r] = f2bf(f.w * scale);
  }
  __syncthreads();

  const int wr = t >> 3;
  const int w8 = (t & 7) * 8;
  #pragma unroll
  for (int it = 0; it < 2; it++) {
    const int n = it * 32 + wr;
    unsigned short o[8];
    #pragma unroll
    for (int j = 0; j < 8; j++) o[j] = TS[n * 65 + w8 + j];
    *(int4*)(dst + (size_t)(bx * 64 + n) * 1024 + by * 64 + w8) = *(const int4*)o;
  }
}

// ---------------------------------------------------------------------------
// gemm256 (v1 schedule): C = A @ Bt^T (bf16, f32 acc)
// 256x256 tile, BK=64, 8 waves (2M x 4N), 128 KiB LDS double-buffer,
// 8-phase counted-vmcnt schedule, st_16x32 swizzle via pre-swizzled source,
// setprio, and NEW round-7 XCD mapping: each XCD owns an 8-m-tile BAND
// (A window 4MB = L2-resident) x all n-tiles. Old mapping gave each XCD one
// n-column x all 64 m-tiles -> full 32MB A stream per XCD L2 (FETCH 222MB,
// 5.8x compulsory). New: lm=(wg>>3)&7, nt=wg>>6, m0=(xcd*8+lm), n0=nt.
// ---------------------------------------------------------------------------
template <bool C_F32>
__global__ __launch_bounds__(512, 2) void gemm256(
    const unsigned short* __restrict__ A,
    const unsigned short* __restrict__ Bt,
    void* __restrict__ Cv,
    int ldc)
{
  // [buf][mat A=0/B=1][quarter][4096 ushorts = 8KB]
  __shared__ __align__(16) unsigned short L[2][2][4][4096];

  const int t    = threadIdx.x;
  const int wave = t >> 6;
  const int lane = t & 63;
  const int l15  = lane & 15;
  const int q4   = lane >> 4;
  const int wm   = wave >> 2;        // 0..1 : 128-row band
  const int wn   = wave & 3;         // 0..3 : 64-col band

  // XCD-band mapping (bijective: nwg = 8 xcd x 8 lm x NT). M = 16384 fixed.
  const int wg  = blockIdx.x;
  const int xcd = wg & 7;
  const int lm  = (wg >> 3) & 7;
  const int nt  = wg >> 6;
  const int m0  = ((xcd << 3) + lm) << 8;
  const int n0  = nt << 8;

  const int srow = ((wave >> 1) << 4) + (lane >> 2);
  const int scol = ((wave & 1) << 5) + (((lane & 3) << 3) ^ (((lane >> 5) & 1) << 4));
  const size_t laneoff = (size_t)srow * 1024 + scol;
  const unsigned short* Ab = A  + (size_t)m0 * 1024 + laneoff;
  const unsigned short* Bb = Bt + (size_t)n0 * 1024 + laneoff;

  const int rdoff = l15 * 32 + ((q4 * 8) ^ (((l15 >> 3) & 1) << 4));

#define SA_(d, q, kt) gl2lds16(Ab + ((size_t)(q) * 64) * 1024 + (size_t)(kt) * 64, \
                               &L[d][0][q][0] + wave * 512)
#define SB_(d, q, kt) gl2lds16(Bb + ((size_t)(q) * 64) * 1024 + (size_t)(kt) * 64, \
                               &L[d][1][q][0] + wave * 512)
#define LDA8(d, i, kk) (*(const bf16x8*)(&L[d][0][wm * 2 + ((i) >> 2)][0] + \
                        ((((i) & 3) * 2 + (kk)) * 512) + rdoff))
#define LDB8(d, j, kk) (*(const bf16x8*)(&L[d][1][wn][0] + \
                        ((((j) * 2 + (kk))) * 512) + rdoff))
#define BAR()   asm volatile("s_barrier" ::: "memory")
#define LGKM0() asm volatile("s_waitcnt lgkmcnt(0)" ::: "memory")
#define VMW(n)  asm volatile("s_waitcnt vmcnt(" #n ")" ::: "memory")
#define MFMA_(av, bv, cv) __builtin_amdgcn_mfma_f32_16x16x32_bf16(av, bv, cv, 0, 0, 0)

  f32x4 acc[8][4];
  #pragma unroll
  for (int i = 0; i < 8; ++i)
    #pragma unroll
    for (int j = 0; j < 4; ++j) acc[i][j] = (f32x4){0.f, 0.f, 0.f, 0.f};

  // Prologue:
  SB_(0,0,0); SB_(0,1,0); SB_(0,2,0); SB_(0,3,0); SA_(0,0,0); SA_(0,2,0);
  SA_(0,1,0); SA_(0,3,0);
  SB_(1,0,1); SB_(1,1,1); SB_(1,2,1); SB_(1,3,1); SA_(1,0,1); SA_(1,2,1);
  VMW(8); BAR();   // T0:{Bq*,Aq0,Aq2} landed; 8 in flight

  #pragma unroll 1
  for (int it = 0; it < 8; ++it) {
    const int t1 = 2 * it + 1;
    const int s2 = (2 * it + 2) & 15;
    const int s3 = (2 * it + 3) & 15;
    bf16x8 a[4][2], b[4][2];

    // ---- P0
    #pragma unroll
    for (int ii = 0; ii < 4; ++ii) { a[ii][0] = LDA8(0, ii, 0); a[ii][1] = LDA8(0, ii, 1); }
    #pragma unroll
    for (int jj = 0; jj < 4; ++jj) { b[jj][0] = LDB8(0, jj, 0); b[jj][1] = LDB8(0, jj, 1); }
    SA_(1, 1, t1); SA_(1, 3, t1);
    BAR(); LGKM0();
    __builtin_amdgcn_s_setprio(1);
    #pragma unroll
    for (int ii = 0; ii < 4; ++ii)
      #pragma unroll
      for (int jj = 0; jj < 2; ++jj) {
        acc[ii][jj] = MFMA_(a[ii][0], b[jj][0], acc[ii][jj]);
        acc[ii][jj] = MFMA_(a[ii][1], b[jj][1], acc[ii][jj]);
      }
    __builtin_amdgcn_s_setprio(0);
    BAR();

    // ---- P1
    SB_(0, 0, s2); SB_(0, 1, s2);
    BAR();
    __builtin_amdgcn_s_setprio(1);
    #pragma unroll
    for (int ii = 0; ii < 4; ++ii)
      #pragma unroll
      for (int jj = 2; jj < 4; ++jj) {
        acc[ii][jj] = MFMA_(a[ii][0], b[jj][0], acc[ii][jj]);
        acc[ii][jj] = MFMA_(a[ii][1], b[jj][1], acc[ii][jj]);
      }
    __builtin_amdgcn_s_setprio(0);
    VMW(10); BAR();

    // ---- P2
    #pragma unroll
    for (int ii = 0; ii < 4; ++ii) { a[ii][0] = LDA8(0, 4 + ii, 0); a[ii][1] = LDA8(0, 4 + ii, 1); }
    SB_(0, 2, s2); SB_(0, 3, s2);
    BAR(); LGKM0();
    __builtin_amdgcn_s_setprio(1);
    #pragma unroll
    for (int ii = 0; ii < 4; ++ii)
      #pragma unroll
      for (int jj = 2; jj < 4; ++jj) {
        acc[4 + ii][jj] = MFMA_(a[ii][0], b[jj][0], acc[4 + ii][jj]);
        acc[4 + ii][jj] = MFMA_(a[ii][1], b[jj][1], acc[4 + ii][jj]);
      }
    __builtin_amdgcn_s_setprio(0);
    BAR();

    // ---- P3
    SA_(0, 0, s2); SA_(0, 2, s2);
    BAR();
    __builtin_amdgcn_s_setprio(1);
    #pragma unroll
    for (int ii = 0; ii < 4; ++ii)
      #pragma unroll
      for (int jj = 0; jj < 2; ++jj) {
        acc[4 + ii][jj] = MFMA_(a[ii][0], b[jj][0], acc[4 + ii][jj]);
        acc[4 + ii][jj] = MFMA_(a[ii][1], b[jj][1], acc[4 + ii][jj]);
      }
    __builtin_amdgcn_s_setprio(0);
    VMW(8); BAR();

    // ---- P4
    #pragma unroll
    for (int ii = 0; ii < 4; ++ii) { a[ii][0] = LDA8(1, ii, 0); a[ii][1] = LDA8(1, ii, 1); }
    #pragma unroll
    for (int jj = 0; jj < 4; ++jj) { b[jj][0] = LDB8(1, jj, 0); b[jj][1] = LDB8(1, jj, 1); }
    SA_(0, 1, s2); SA_(0, 3, s2);
    BAR(); LGKM0();
    __builtin_amdgcn_s_setprio(1);
    #pragma unroll
    for (int ii = 0; ii < 4; ++ii)
      #pragma unroll
      for (int jj = 0; jj < 2; ++jj) {
        acc[ii][jj] = MFMA_(a[ii][0], b[jj][0], acc[ii][jj]);
        acc[ii][jj] = MFMA_(a[ii][1], b[jj][1], acc[ii][jj]);
      }
    __builtin_amdgcn_s_setprio(0);
    BAR();

    // ---- P5
    SB_(1, 0, s3); SB_(1, 1, s3);
    BAR();
    __builtin_amdgcn_s_setprio(1);
    #pragma unroll
    for (int ii = 0; ii < 4; ++ii)
      #pragma unroll
      for (int jj = 2; jj < 4; ++jj) {
        acc[ii][jj] = MFMA_(a[ii][0], b[jj][0], acc[ii][jj]);
        acc[ii][jj] = MFMA_(a[ii][1], b[jj][1], acc[ii][jj]);
      }
    __builtin_amdgcn_s_setprio(0);
    VMW(10); BAR();

    // ---- P6
    #pragma unroll
    for (int ii = 0; ii < 4; ++ii) { a[ii][0] = LDA8(1, 4 + ii, 0); a[ii][1] = LDA8(1, 4 + ii, 1); }
    SB_(1, 2, s3); SB_(1, 3, s3);
    BAR(); LGKM0();
    __builtin_amdgcn_s_setprio(1);
    #pragma unroll
    for (int ii = 0; ii < 4; ++ii)
      #pragma unroll
      for (int jj = 2; jj < 4; ++jj) {
        acc[4 + ii][jj] = MFMA_(a[ii][0], b[jj][0], acc[4 + ii][jj]);
        acc[4 + ii][jj] = MFMA_(a[ii][1], b[jj][1], acc[4 + ii][jj]);
      }
    __builtin_amdgcn_s_setprio(0);
    BAR();

    // ---- P7
    SA_(1, 0, s3); SA_(1, 2, s3);
    BAR();
    __builtin_amdgcn_s_setprio(1);
    #pragma unroll
    for (int ii = 0; ii < 4; ++ii)
      #pragma unroll
      for (int jj = 0; jj < 2; ++jj) {
        acc[4 + ii][jj] = MFMA_(a[ii][0], b[jj][0], acc[4 + ii][jj]);
        acc[4 + ii][jj] = MFMA_(a[ii][1], b[jj][1], acc[4 + ii][jj]);
      }
    __builtin_amdgcn_s_setprio(0);
    VMW(8); BAR();
  }

  // Epilogue: C write (each wave owns 128x64 at (wm*128, wn*64))
  #pragma unroll
  for (int i = 0; i < 8; ++i) {
    #pragma unroll
    for (int j = 0; j < 4; ++j) {
      const int col = n0 + wn * 64 + j * 16 + l15;
      #pragma unroll
      for (int r = 0; r < 4; ++r) {
        const int row = m0 + wm * 128 + i * 16 + q4 * 4 + r;
        if (C_F32) ((float*)Cv)[(size_t)row * ldc + col] = acc[i][j][r];
        else ((unsigned short*)Cv)[(size_t)row * ldc + col] = f2bf(acc[i][j][r]);
      }
    }
  }
  VMW(0);  // drain straggler LDS-DMA before endpgm (next block reuses this LDS)

#undef SA_
#undef SB_
#undef LDA8
#undef LDB8
#undef BAR
#undef LGKM0
#undef VMW
#undef MFMA_
}

// ---------------------------------------------------------------------------
// Span kernel (v2, round-5 known-good): per (chunk c, head h), 1 wave.
// Dual-accumulator + unroll to pipeline LDS-read latency in the 64-loops.
// ---------------------------------------------------------------------------
__global__ __launch_bounds__(64) void span_kernel(
    const unsigned short* __restrict__ qkv,
    unsigned short* __restrict__ spanK,   // [256][16][64]
    unsigned short* __restrict__ spanV)   // [256][16][64]
{
  __shared__ unsigned short QS[64 * 66], KS[64 * 66], VS[64 * 66];
  __shared__ float mqs[64], ws[64];

  const int c = blockIdx.x;
  const int h = blockIdx.y;
  const int b = c >> 6, n = c & 63;
  const int t = threadIdx.x;

  const size_t rowbase = ((size_t)(b * LL + n * SEGC + t)) * 3072 + h * 64;
  #pragma unroll
  for (int j = 0; j < 4; j++) {
    g2lds16(QS + t * 66 + j * 16, qkv + rowbase + j * 16);
    g2lds16(KS + t * 66 + j * 16, qkv + rowbase + 1024 + j * 16);
    g2lds16(VS + t * 66 + j * 16, qkv + rowbase + 2048 + j * 16);
  }
  __syncthreads();

  float mqa = -3.0e38f, mqb = -3.0e38f, ska = -3.0e38f, skc = -3.0e38f;
  #pragma unroll 8
  for (int r = 0; r < 64; r += 2) {
    mqa = fmaxf(mqa, bf2f(QS[r * 66 + t]));
    mqb = fmaxf(mqb, bf2f(QS[(r + 1) * 66 + t]));
    ska = fmaxf(ska, bf2f(KS[r * 66 + t]));
    skc = fmaxf(skc, bf2f(KS[(r + 1) * 66 + t]));
  }
  mqs[t] = fmaxf(mqa, mqb);
  spanK[((size_t)c * 16 + h) * 64 + t] = f2bf(fmaxf(ska, skc));
  __syncthreads();

  float l0 = 0.f, l1 = 0.f;
  #pragma unroll 8
  for (int d = 0; d < 64; d += 2) {
    l0 += mqs[d] * bf2f(KS[t * 66 + d]);
    l1 += mqs[d + 1] * bf2f(KS[t * 66 + d + 1]);
  }
  float logit = l0 + l1;
  float m = logit;
  #pragma unroll
  for (int off = 32; off; off >>= 1) m = fmaxf(m, __shfl_xor(m, off, 64));
  float e = __expf(logit - m);
  float s = e;
  #pragma unroll
  for (int off = 32; off; off >>= 1) s += __shfl_xor(s, off, 64);
  ws[t] = e / s;
  __syncthreads();

  float sv0 = 0.f, sv1 = 0.f;
  #pragma unroll 8
  for (int kk = 0; kk < 64; kk += 2) {
    sv0 += ws[kk] * bf2f(VS[kk * 66 + t]);
    sv1 += ws[kk + 1] * bf2f(VS[(kk + 1) * 66 + t]);
  }
  spanV[((size_t)c * 16 + h) * 64 + t] = f2bf(sv0 + sv1);
}

// ---------------------------------------------------------------------------
// Joint attention kernel (MFMA): per (chunk c, head h), 4 waves.
// v3: K-joint (local K + spanK) staged into LDS KJ[128][72] via coalesced
// g2lds16 (4 threads/row = 128B contiguous). VT staging keeps the v2 XOR
// swizzle (element-verified in round 3).
// ---------------------------------------------------------------------------
__global__ __launch_bounds__(256) void attn_kernel(
    const unsigned short* __restrict__ qkv,
    const unsigned short* __restrict__ spanK,
    const unsigned short* __restrict__ spanV,
    unsigned short* __restrict__ att)
{
  __shared__ __align__(16) unsigned short KJ[128 * 72];  // [r][72]: r<64 local K, r>=64 spanK
  __shared__ __align__(16) unsigned short VT[64 * 136];  // [f][k'-swizzled]
  __shared__ __align__(16) unsigned short WL[64 * 136];  // [att row][k'] weights

  const int c = blockIdx.x;
  const int h = blockIdx.y;
  const int b = c >> 6, n = c & 63;
  const int t = threadIdx.x;
  const int wave = t >> 6;
  const int lane = t & 63;
  const int l15  = lane & 15;
  const int q4   = lane >> 4;

  // ---- stage K-joint into KJ (coalesced: 4 threads x 32B = 128B per row)
  {
    const int r  = t >> 2;            // 0..63
    const int qq = (t & 3) * 16;      // 0,16,32,48 (u16)
    g2lds16(KJ + r * 72 + qq,
            qkv + ((size_t)(b * LL + n * SEGC + r)) * 3072 + 1024 + h * 64 + qq);
    g2lds16(KJ + (64 + r) * 72 + qq,
            spanK + ((size_t)(b * 64 + r) * 16 + h) * 64 + qq);
  }

  // ---- stage V' transposed into VT (v2 swizzle)
  #pragma unroll
  for (int it = 0; it < 4; it++) {
    const int idx = t + 256 * it;
    const int kp  = idx >> 3;           // joint key 0..127
    const int fc  = (idx & 7) * 8;
    const unsigned short* src;
    if (kp < 64)
      src = qkv + ((size_t)(b * LL + n * SEGC + kp)) * 3072 + 2048 + h * 64 + fc;
    else
      src = spanV + ((size_t)(b * 64 + (kp - 64)) * 16 + h) * 64 + fc;
    int4 val = *(const int4*)src;
    const unsigned short* e = (const unsigned short*)&val;
    const int kb = kp >> 3;             // k'-block 0..15
    #pragma unroll
    for (int i = 0; i < 8; i++) {
      const int f  = fc + i;
      const int nb = (kb & 8) | ((kb ^ (f >> 3)) & 7);   // swizzled block
      VT[f * 136 + nb * 8 + (kp & 7)] = e[i];
    }
  }

  // Q fragments: direct global (read once, no reuse)
  bf16x8 af[2];
  {
    const size_t qbase = ((size_t)(b * LL + n * SEGC + wave * 16 + l15)) * 3072
                         + h * 64 + q4 * 8;
    af[0] = *(const bf16x8*)(qkv + qbase);
    af[1] = *(const bf16x8*)(qkv + qbase + 32);
  }

  __syncthreads();   // KJ + VT complete

  f32x4 accl[8];
  #pragma unroll
  for (int tt = 0; tt < 8; tt++) accl[tt] = (f32x4){0.f, 0.f, 0.f, 0.f};

  #pragma unroll
  for (int s = 0; s < 2; s++) {
    bf16x8 bfr[8];
    #pragma unroll
    for (int tt = 0; tt < 8; tt++)
      bfr[tt] = *(const bf16x8*)(KJ + (tt * 16 + l15) * 72 + s * 32 + q4 * 8);
    #pragma unroll
    for (int tt = 0; tt < 8; tt++)
      accl[tt] = __builtin_amdgcn_mfma_f32_16x16x32_bf16(af[s], bfr[tt], accl[tt], 0, 0, 0);
  }

  #pragma unroll
  for (int tt = 0; tt < 8; tt++) {
    const int col = (tt & 3) * 16 + l15;
    #pragma unroll
    for (int rr = 0; rr < 4; rr++) {
      const int r_att = wave * 16 + q4 * 4 + rr;
      const bool valid = (tt < 4) ? (col <= r_att) : (col < n);
      if (!valid) accl[tt][rr] = NEGV;
    }
  }

  #pragma unroll
  for (int rr = 0; rr < 4; rr++) {
    float mx = accl[0][rr];
    #pragma unroll
    for (int tt = 1; tt < 8; tt++) mx = fmaxf(mx, accl[tt][rr]);
    #pragma unroll
    for (int msk = 1; msk < 16; msk <<= 1) mx = fmaxf(mx, __shfl_xor(mx, msk, 64));
    float sm = 0.f;
    float ex[8];
    #pragma unroll
    for (int tt = 0; tt < 8; tt++) { ex[tt] = __expf(accl[tt][rr] - mx); sm += ex[tt]; }
    #pragma unroll
    for (int msk = 1; msk < 16; msk <<= 1) sm += __shfl_xor(sm, msk, 64);
    const float inv = 1.0f / sm;
    const int r_att = wave * 16 + q4 * 4 + rr;
    #pragma unroll
    for (int tt = 0; tt < 8; tt++) {
      const int colj = (tt < 4) ? (tt * 16 + l15) : (64 + (tt - 4) * 16 + l15);
      WL[r_att * 136 + colj] = f2bf(ex[tt] * inv);
    }
  }

  __syncthreads();

  f32x4 accm[4];
  #pragma unroll
  for (int j = 0; j < 4; j++) accm[j] = (f32x4){0.f, 0.f, 0.f, 0.f};
  #pragma unroll
  for (int s = 0; s < 4; s++) {
    const bf16x8 aw = *(const bf16x8*)(WL + (wave * 16 + l15) * 136 + s * 32 + q4 * 8);
    #pragma unroll
    for (int j = 0; j < 4; j++) {
      const int f  = j * 16 + l15;
      const int kb = s * 4 + q4;                          // k'-block 0..15
      const int nb = (kb & 8) | ((kb ^ (f >> 3)) & 7);    // same swizzle as write
      const bf16x8 bv = *(const bf16x8*)(VT + f * 136 + nb * 8);
      accm[j] = __builtin_amdgcn_mfma_f32_16x16x32_bf16(aw, bv, accm[j], 0, 0, 0);
    }
  }

  #pragma unroll
  for (int j = 0; j < 4; j++) {
    #pragma unroll
    for (int rr = 0; rr < 4; rr++) {
      const int row = wave * 16 + q4 * 4 + rr;
      const int col = j * 16 + l15;
      att[((size_t)(b * LL + n * SEGC + row)) * 1024 + h * 64 + col] = f2bf(accm[j][rr]);
    }
  }
}

// ---------------------------------------------------------------------------
extern "C" void kernel_launch(void* const* d_in, const int* in_sizes, int n_in,
                              void* d_out, int out_size, void* d_ws, size_t ws_size,
                              hipStream_t stream) {
  const float* x  = (const float*)d_in[0];
  const float* wq = (const float*)d_in[1];
  const float* wk = (const float*)d_in[2];
  const float* wv = (const float*)d_in[3];
  const float* wo = (const float*)d_in[4];
  float* out = (float*)d_out;

  unsigned short* wsp   = (unsigned short*)d_ws;
  unsigned short* xb    = wsp;                       // 16,777,216 (aliased as attb later)
  unsigned short* qkv   = xb + 16777216;             // 50,331,648
  unsigned short* WqkvT = qkv + 50331648;            //  3,145,728
  unsigned short* woT   = WqkvT + 3145728;           //  1,048,576
  unsigned short* skb   = woT + 1048576;             //    262,144
  unsigned short* svb   = skb + 262144;              //    262,144
  unsigned short* attb  = xb;   // alias: xb dead after QKV GEMM

  cvt_x<<<8192, 256, 0, stream>>>(x, xb);
  transpose_w<<<dim3(16, 16, 4), 256, 0, stream>>>(wq, wk, wv, wo, WqkvT, woT);
  // QKV: M=16384, N=3072 -> 64 x 12 = 768 tiles (768 % 8 == 0)
  gemm256<false><<<768, 512, 0, stream>>>(xb, WqkvT, (void*)qkv, 3072);
  span_kernel<<<dim3(256, 16), 64, 0, stream>>>(qkv, skb, svb);
  attn_kernel<<<dim3(256, 16), 256, 0, stream>>>(qkv, skb, svb, attb);
  // out-proj: M=16384, N=1024 -> 64 x 4 = 256 tiles (256 % 8 == 0)
  gemm256<true><<<256, 512, 0, stream>>>(attb, woT, (void*)out, 1024);
}